// Round 6
// baseline (218.200 us; speedup 1.0000x reference)
//
#include <hip/hip_runtime.h>
#include <hip/hip_bf16.h>

typedef unsigned short u16;
typedef unsigned int u32;
typedef __attribute__((ext_vector_type(8))) __bf16 bf16x8;
typedef __attribute__((ext_vector_type(4))) float f32x4;

#define KCTX 32
#define INF_ 608
#define HID_ 384

// ws layout (bytes). ws is >= 256 MiB (poison-fill WRITE_SIZE evidence, r2).
#define HB_OFF  0                     // hb  [16384,608] bf16 = 19,922,944
#define WH_OFF  19922944              // Wh  [16384,384] bf16 = 12,582,912
#define BT_OFF  32505856              // Bt  [384,608]  bf16 =    466,944
#define V_OFF   32972800              // v   [608] f32        =      2,432
#define SI_OFF  32975232              // si  [16384] f32      =     65,536
#define SJ_OFF  33040768              // sj  [16384] f32      =     65,536
#define AJF_OFF 33106304              // ajf [384] f32        =      1,536
#define ABF_OFF 33107840              // abf [1] f32

__device__ __forceinline__ float bfu(u16 u)  { return __uint_as_float(((u32)u) << 16); }
__device__ __forceinline__ float bflo(u32 u) { return __uint_as_float(u << 16); }
__device__ __forceinline__ float bfhi(u32 u) { return __uint_as_float(u & 0xffff0000u); }
__device__ __forceinline__ u16 f2bf(float x) {            // round-to-nearest-even
  u32 u = __float_as_uint(x);
  return (u16)((u + 0x7fffu + ((u >> 16) & 1u)) >> 16);
}
__device__ __forceinline__ void async_ld16(const void* g, void* l) {
  __builtin_amdgcn_global_load_lds(
      (const __attribute__((address_space(1))) u32*)g,
      (__attribute__((address_space(3))) u32*)l, 16, 0, 0);
}

// ---- per-wave runtime dtype detection (wave-uniform, L2-hot; validated r2-r5) ----
__device__ __forceinline__ int detect_f32(const u32* hw) {
  const u32 w = hw[threadIdx.x & 63];
  const int e = (int)((w >> 7) & 0xffu);
  const unsigned long long mb = __ballot(e > 134 || e < 100);
  return __popcll(mb) >= 16;
}
__device__ __forceinline__ int detect_i64(const int* ci) {
  const int hi = ci[2 * (threadIdx.x & 63) + 1];
  const unsigned long long mz = __ballot(hi == 0 || hi == -1);
  return __popcll(mz) >= 48;
}

// ---- prep: Bt = bf16(W_j^T), v = W_i@a_i, ajf/abf fp32, zero sj ----
__global__ __launch_bounds__(256) void prep_kernel(
    const void* __restrict__ h, const void* __restrict__ Wi,
    const void* __restrict__ Wj, const void* __restrict__ ai,
    const void* __restrict__ aj, const void* __restrict__ ab,
    u16* __restrict__ Bt, float* __restrict__ v, float* __restrict__ sj,
    float* __restrict__ ajf, float* __restrict__ abf) {
  __shared__ u16 tile[64][65];
  const int f32m = detect_f32((const u32*)h);
  const int bid = blockIdx.x, tid = threadIdx.x;
  if (bid < 60) {                                  // transpose: 10(f) x 6(h) tiles
    const int ft = bid / 6, ht = bid - ft * 6;
    const int f0 = ft * 64, h0 = ht * 64;
    const int ln = tid & 63, fg = tid >> 6;
#pragma unroll
    for (int rr = 0; rr < 16; ++rr) {              // read: lanes contiguous in h
      const int fl = fg * 16 + rr;
      const int f = f0 + fl;
      if (f < INF_)
        tile[fl][ln] = f32m ? f2bf(((const float*)Wj)[(size_t)f * HID_ + h0 + ln])
                            : ((const u16*)Wj)[(size_t)f * HID_ + h0 + ln];
    }
    __syncthreads();
#pragma unroll
    for (int rr = 0; rr < 16; ++rr) {              // write: lanes contiguous in f
      const int hl = fg * 16 + rr;
      const int f = f0 + ln;
      if (f < INF_) Bt[(size_t)(h0 + hl) * INF_ + f] = tile[ln][hl];
    }
  } else if (bid < 98) {                           // v: 16-lane group per row
    const int t = (bid - 60) * 16 + (tid >> 4);    // row 0..607
    const int sl = tid & 15;
    if (t < INF_) {
      float s = 0.f;
      if (f32m) {
        const float4* wi = (const float4*)((const float*)Wi + (size_t)t * HID_);
        const float4* a4 = (const float4*)ai;
        for (int c = sl; c < 96; c += 16) {
          float4 x = wi[c], y = a4[c];
          s += x.x * y.x + x.y * y.y + x.z * y.z + x.w * y.w;
        }
      } else {
        const uint4* wi = (const uint4*)((const u16*)Wi + (size_t)t * HID_);
        const uint4* a4 = (const uint4*)ai;
        for (int c = sl; c < 48; c += 16) {
          uint4 x = wi[c], y = a4[c];
          s += bflo(x.x) * bflo(y.x) + bfhi(x.x) * bfhi(y.x)
             + bflo(x.y) * bflo(y.y) + bfhi(x.y) * bfhi(y.y)
             + bflo(x.z) * bflo(y.z) + bfhi(x.z) * bfhi(y.z)
             + bflo(x.w) * bflo(y.w) + bfhi(x.w) * bfhi(y.w);
        }
      }
      s += __shfl_xor(s, 1); s += __shfl_xor(s, 2);
      s += __shfl_xor(s, 4); s += __shfl_xor(s, 8);
      if (sl == 0) v[t] = s;
    }
  } else {                                         // zero sj, build ajf/abf
#pragma unroll 8
    for (int j = 0; j < 64; ++j) sj[j * 256 + tid] = 0.f;
    for (int j = tid; j < HID_; j += 256)
      ajf[j] = f32m ? ((const float*)aj)[j] : bfu(((const u16*)aj)[j]);
    if (tid == 0)
      abf[0] = f32m ? ((const float*)ab)[0] : bfu(((const u16*)ab)[0]);
  }
}

// ---- conv: read h once (fp32-exact si), emit bf16 hb ----
__global__ __launch_bounds__(256) void conv_kernel(
    const void* __restrict__ h, const float* __restrict__ v,
    u16* __restrict__ hb, float* __restrict__ si) {
  const int f32m = detect_f32((const u32*)h);
  const int wv = threadIdx.x >> 6, lane = threadIdx.x & 63;
  const int n = blockIdx.x * 4 + wv;
  uint4* hbrow = (uint4*)(hb + (size_t)n * INF_);          // 76 uint4 per row
  const float4* v4 = (const float4*)v;
  float sum = 0.f;
  if (f32m) {
    const float4* hr = (const float4*)((const float*)h + (size_t)n * INF_);
    for (int c = lane; c < 76; c += 64) {
      float4 x0 = hr[2 * c], x1 = hr[2 * c + 1];
      uint4 o;
      o.x = (u32)f2bf(x0.x) | ((u32)f2bf(x0.y) << 16);
      o.y = (u32)f2bf(x0.z) | ((u32)f2bf(x0.w) << 16);
      o.z = (u32)f2bf(x1.x) | ((u32)f2bf(x1.y) << 16);
      o.w = (u32)f2bf(x1.z) | ((u32)f2bf(x1.w) << 16);
      hbrow[c] = o;
      float4 w0 = v4[2 * c], w1 = v4[2 * c + 1];
      sum += x0.x * w0.x + x0.y * w0.y + x0.z * w0.z + x0.w * w0.w
           + x1.x * w1.x + x1.y * w1.y + x1.z * w1.z + x1.w * w1.w;
    }
  } else {
    const uint4* hr = (const uint4*)((const u16*)h + (size_t)n * INF_);
    for (int c = lane; c < 76; c += 64) {
      uint4 x = hr[c];
      hbrow[c] = x;
      float4 w0 = v4[2 * c], w1 = v4[2 * c + 1];
      sum += bflo(x.x) * w0.x + bfhi(x.x) * w0.y + bflo(x.y) * w0.z + bfhi(x.y) * w0.w
           + bflo(x.z) * w1.x + bfhi(x.z) * w1.y + bflo(x.w) * w1.z + bfhi(x.w) * w1.w;
    }
  }
#pragma unroll
  for (int o = 32; o; o >>= 1) sum += __shfl_xor(sum, o);
  if (lane == 0) si[n] = sum;
}

// ---- GEMM: Wh(bf16) = hb @ W_j, fused sj = Wh.a_j (fp32 acc, single path) ----
__global__ __launch_bounds__(256, 2) void gemm_kernel(
    const u16* __restrict__ A, const u16* __restrict__ Bt,
    u16* __restrict__ C, const float* __restrict__ ajf, float* __restrict__ sj) {
  __shared__ __align__(16) u16 As[128][32];
  __shared__ __align__(16) u16 Bs[128][32];
  const int tid  = threadIdx.x;
  const int lane = tid & 63;
  const int wave = tid >> 6;
  const int row0 = blockIdx.x * 128;
  const int col0 = blockIdx.y * 128;
  const int wm = (wave & 1) * 64;
  const int wn = (wave >> 1) * 64;

  f32x4 acc[4][4];
#pragma unroll
  for (int i = 0; i < 4; ++i)
#pragma unroll
    for (int j = 0; j < 4; ++j) acc[i][j] = (f32x4){0.f, 0.f, 0.f, 0.f};

  const int c0 = tid, c1 = tid + 256;              // 16B chunks 0..511
  const int rA0 = c0 >> 2, kc0 = (c0 & 3) * 16;
  const int rA1 = c1 >> 2, kc1 = (c1 & 3) * 16;
  const char* Ab  = (const char*)A;
  const char* Btb = (const char*)Bt;

  for (int kt = 0; kt < 19; ++kt) {
    const size_t kb = (size_t)kt * 64;             // 32 bf16 = 64 B of k
    async_ld16(Ab  + (size_t)(row0 + rA0) * 1216 + kb + kc0, (char*)As + c0 * 16);
    async_ld16(Ab  + (size_t)(row0 + rA1) * 1216 + kb + kc1, (char*)As + c1 * 16);
    async_ld16(Btb + (size_t)(col0 + rA0) * 1216 + kb + kc0, (char*)Bs + c0 * 16);
    async_ld16(Btb + (size_t)(col0 + rA1) * 1216 + kb + kc1, (char*)Bs + c1 * 16);
    __syncthreads();

    const int kk = (lane >> 4) * 8;
    const int lm0 = lane & 15;
    bf16x8 af[4], bfr[4];
#pragma unroll
    for (int i = 0; i < 4; ++i) af[i]  = *(const bf16x8*)&As[wm + i * 16 + lm0][kk];
#pragma unroll
    for (int i = 0; i < 4; ++i) bfr[i] = *(const bf16x8*)&Bs[wn + i * 16 + lm0][kk];
#pragma unroll
    for (int im = 0; im < 4; ++im)
#pragma unroll
      for (int in = 0; in < 4; ++in)
        acc[im][in] = __builtin_amdgcn_mfma_f32_16x16x32_bf16(
            af[im], bfr[in], acc[im][in], 0, 0, 0);
    __syncthreads();
  }

  const int lm = lane & 15, lq = lane >> 4;
#pragma unroll
  for (int im = 0; im < 4; ++im)
#pragma unroll
    for (int in = 0; in < 4; ++in) {
      const int colg = col0 + wn + in * 16 + lm;
#pragma unroll
      for (int r = 0; r < 4; ++r) {
        const int rowg = row0 + wm + im * 16 + lq * 4 + r;
        C[(size_t)rowg * HID_ + colg] = f2bf(acc[im][in][r]);
      }
    }
  // fused sj epilogue
  float ajv[4];
#pragma unroll
  for (int in = 0; in < 4; ++in) ajv[in] = ajf[col0 + wn + in * 16 + lm];
#pragma unroll
  for (int im = 0; im < 4; ++im)
#pragma unroll
    for (int r = 0; r < 4; ++r) {
      float p = acc[im][0][r] * ajv[0] + acc[im][1][r] * ajv[1]
              + acc[im][2][r] * ajv[2] + acc[im][3][r] * ajv[3];
      p += __shfl_xor(p, 1); p += __shfl_xor(p, 2);
      p += __shfl_xor(p, 4); p += __shfl_xor(p, 8);
      if (lm == 0) atomicAdd(&sj[row0 + wm + im * 16 + lq * 4 + r], p);
    }
}

// ---- attn: scores + softmax (shfl) + gather, 4-way column-sliced for XCD-L2
// residency. quarter = blockIdx.x & 3; with round-robin block->XCD dispatch each
// XCD touches a 3.15 MB slice of Wh (< 4 MiB L2). Request count per row-k is
// unchanged (48 lanes x 4 B = 3 lines x 4 quarters = 12 lines, same as 48x16B).
__global__ __launch_bounds__(256) void attn_kernel(
    const void* __restrict__ h, const int* __restrict__ ci,
    const float* __restrict__ si, const float* __restrict__ sj,
    const float* __restrict__ abf, const u16* __restrict__ Wh,
    void* __restrict__ out) {
  const int f32m = detect_f32((const u32*)h);
  const int i64  = detect_i64(ci);
  const int wv = threadIdx.x >> 6, lane = threadIdx.x & 63;
  const int q = blockIdx.x & 3;                    // column quarter (XCD-affine)
  const int n = (blockIdx.x >> 2) * 4 + wv;        // row

  float att = 0.f; int idxv = 0;
  if (lane < 32) {
    const size_t t = (size_t)n * KCTX + lane;
    int idx;
    if (i64) { int lo = ci[2 * t], hi = ci[2 * t + 1]; idx = (hi < 0) ? -1 : lo; }
    else     { idx = ci[t]; }
    const bool valid = idx >= 0;
    const float sjv = valid ? sj[idx] : 0.f;
    float raw = si[n] + sjv + abf[0];
    float lr = raw > 0.f ? raw : 0.2f * raw;
    float s = valid ? lr : -9e15f;
    float m = s;
#pragma unroll
    for (int o = 16; o; o >>= 1) m = fmaxf(m, __shfl_xor(m, o, 32));
    float p = __expf(s - m);
    float d = p;
#pragma unroll
    for (int o = 16; o; o >>= 1) d += __shfl_xor(d, o, 32);
    att = valid ? p / d : 0.f;
    idxv = valid ? idx : 0;
  }

  // gather quarter q: lanes 0..47, one u32 (2 bf16 cols) per lane per k
  const int col2 = q * 48 + lane;                  // u32 index within 192/row
  float a0 = 0.f, a1 = 0.f;
#pragma unroll 4
  for (int k = 0; k < KCTX; ++k) {
    const float w = __shfl(att, k);                // wave-uniform
    const int   j = __shfl(idxv, k);
    if (w != 0.f && lane < 48) {                   // skip padding k's (uniform)
      const u32 x = ((const u32*)(Wh + (u32)j * HID_))[col2];
      a0 += w * bflo(x); a1 += w * bfhi(x);
    }
  }
  if (lane < 48) {
    if (f32m) {
      float2* o2 = (float2*)out;
      o2[(size_t)n * 192 + col2] = (float2){a0, a1};
    } else {
      ((u32*)out)[(size_t)n * 192 + col2] = (u32)f2bf(a0) | ((u32)f2bf(a1) << 16);
    }
  }
}

extern "C" void kernel_launch(void* const* d_in, const int* in_sizes, int n_in,
                              void* d_out, int out_size, void* d_ws, size_t ws_size,
                              hipStream_t stream) {
  const void* h  = d_in[0];
  const int*  ci = (const int*)d_in[1];
  const void* Wi = d_in[2];
  const void* Wj = d_in[3];
  const void* ai = d_in[4];
  const void* aj = d_in[5];
  const void* ab = d_in[6];

  char* ws = (char*)d_ws;
  u16*   hb  = (u16*)(ws + HB_OFF);
  u16*   Wh  = (u16*)(ws + WH_OFF);
  u16*   Bt  = (u16*)(ws + BT_OFF);
  float* v   = (float*)(ws + V_OFF);
  float* si  = (float*)(ws + SI_OFF);
  float* sj  = (float*)(ws + SJ_OFF);
  float* ajf = (float*)(ws + AJF_OFF);
  float* abf = (float*)(ws + ABF_OFF);

  prep_kernel<<<99, 256, 0, stream>>>(h, Wi, Wj, ai, aj, ab, Bt, v, sj, ajf, abf);
  conv_kernel<<<4096, 256, 0, stream>>>(h, v, hb, si);
  dim3 g(128, 3);
  gemm_kernel<<<g, 256, 0, stream>>>(hb, Bt, Wh, ajf, sj);
  attn_kernel<<<16384, 256, 0, stream>>>(h, ci, si, sj, abf, Wh, d_out);
}

// Round 7
// 160.593 us; speedup vs baseline: 1.3587x; 1.3587x over previous
//
#include <hip/hip_runtime.h>
#include <hip/hip_bf16.h>

typedef unsigned short u16;
typedef unsigned int u32;
typedef __attribute__((ext_vector_type(8))) __bf16 bf16x8;
typedef __attribute__((ext_vector_type(4))) float f32x4;

#define KCTX 32
#define INF_ 608
#define HID_ 384

// ws layout (bytes). ws is >= 256 MiB (poison-fill WRITE_SIZE evidence, r2).
#define HB_OFF  0                     // hb  [16384,608] bf16 = 19,922,944
#define WH_OFF  19922944              // Wh  [16384,384] bf16 = 12,582,912
#define BT_OFF  32505856              // Bt  [384,608]  bf16 =    466,944
#define V_OFF   32972800              // v   [608] f32        =      2,432
#define SI_OFF  32975232              // si  [16384] f32      =     65,536
#define SJ_OFF  33040768              // sj  [16384] f32      =     65,536
#define AJF_OFF 33106304              // ajf [384] f32        =      1,536
#define ABF_OFF 33107840              // abf [1] f32

__device__ __forceinline__ float bfu(u16 u)  { return __uint_as_float(((u32)u) << 16); }
__device__ __forceinline__ float bflo(u32 u) { return __uint_as_float(u << 16); }
__device__ __forceinline__ float bfhi(u32 u) { return __uint_as_float(u & 0xffff0000u); }
__device__ __forceinline__ u16 f2bf(float x) {            // round-to-nearest-even
  u32 u = __float_as_uint(x);
  return (u16)((u + 0x7fffu + ((u >> 16) & 1u)) >> 16);
}
__device__ __forceinline__ void async_ld16(const void* g, void* l) {
  __builtin_amdgcn_global_load_lds(
      (const __attribute__((address_space(1))) u32*)g,
      (__attribute__((address_space(3))) u32*)l, 16, 0, 0);
}

// ---- per-wave runtime dtype detection (wave-uniform, L2-hot; validated r2-r6) ----
__device__ __forceinline__ int detect_f32(const u32* hw) {
  const u32 w = hw[threadIdx.x & 63];
  const int e = (int)((w >> 7) & 0xffu);
  const unsigned long long mb = __ballot(e > 134 || e < 100);
  return __popcll(mb) >= 16;
}
__device__ __forceinline__ int detect_i64(const int* ci) {
  const int hi = ci[2 * (threadIdx.x & 63) + 1];
  const unsigned long long mz = __ballot(hi == 0 || hi == -1);
  return __popcll(mz) >= 48;
}

// ---- prep: Bt = bf16(W_j^T), v = W_i@a_i, ajf/abf fp32, zero sj ----
__global__ __launch_bounds__(256) void prep_kernel(
    const void* __restrict__ h, const void* __restrict__ Wi,
    const void* __restrict__ Wj, const void* __restrict__ ai,
    const void* __restrict__ aj, const void* __restrict__ ab,
    u16* __restrict__ Bt, float* __restrict__ v, float* __restrict__ sj,
    float* __restrict__ ajf, float* __restrict__ abf) {
  __shared__ u16 tile[64][65];
  const int f32m = detect_f32((const u32*)h);
  const int bid = blockIdx.x, tid = threadIdx.x;
  if (bid < 60) {                                  // transpose: 10(f) x 6(h) tiles
    const int ft = bid / 6, ht = bid - ft * 6;
    const int f0 = ft * 64, h0 = ht * 64;
    const int ln = tid & 63, fg = tid >> 6;
#pragma unroll
    for (int rr = 0; rr < 16; ++rr) {              // read: lanes contiguous in h
      const int fl = fg * 16 + rr;
      const int f = f0 + fl;
      if (f < INF_)
        tile[fl][ln] = f32m ? f2bf(((const float*)Wj)[(size_t)f * HID_ + h0 + ln])
                            : ((const u16*)Wj)[(size_t)f * HID_ + h0 + ln];
    }
    __syncthreads();
#pragma unroll
    for (int rr = 0; rr < 16; ++rr) {              // write: lanes contiguous in f
      const int hl = fg * 16 + rr;
      const int f = f0 + ln;
      if (f < INF_) Bt[(size_t)(h0 + hl) * INF_ + f] = tile[ln][hl];
    }
  } else if (bid < 98) {                           // v: 16-lane group per row
    const int t = (bid - 60) * 16 + (tid >> 4);    // row 0..607
    const int sl = tid & 15;
    if (t < INF_) {
      float s = 0.f;
      if (f32m) {
        const float4* wi = (const float4*)((const float*)Wi + (size_t)t * HID_);
        const float4* a4 = (const float4*)ai;
        for (int c = sl; c < 96; c += 16) {
          float4 x = wi[c], y = a4[c];
          s += x.x * y.x + x.y * y.y + x.z * y.z + x.w * y.w;
        }
      } else {
        const uint4* wi = (const uint4*)((const u16*)Wi + (size_t)t * HID_);
        const uint4* a4 = (const uint4*)ai;
        for (int c = sl; c < 48; c += 16) {
          uint4 x = wi[c], y = a4[c];
          s += bflo(x.x) * bflo(y.x) + bfhi(x.x) * bfhi(y.x)
             + bflo(x.y) * bflo(y.y) + bfhi(x.y) * bfhi(y.y)
             + bflo(x.z) * bflo(y.z) + bfhi(x.z) * bfhi(y.z)
             + bflo(x.w) * bflo(y.w) + bfhi(x.w) * bfhi(y.w);
        }
      }
      s += __shfl_xor(s, 1); s += __shfl_xor(s, 2);
      s += __shfl_xor(s, 4); s += __shfl_xor(s, 8);
      if (sl == 0) v[t] = s;
    }
  } else {                                         // zero sj, build ajf/abf
#pragma unroll 8
    for (int j = 0; j < 64; ++j) sj[j * 256 + tid] = 0.f;
    for (int j = tid; j < HID_; j += 256)
      ajf[j] = f32m ? ((const float*)aj)[j] : bfu(((const u16*)aj)[j]);
    if (tid == 0)
      abf[0] = f32m ? ((const float*)ab)[0] : bfu(((const u16*)ab)[0]);
  }
}

// ---- conv: read h once (fp32-exact si), emit bf16 hb ----
__global__ __launch_bounds__(256) void conv_kernel(
    const void* __restrict__ h, const float* __restrict__ v,
    u16* __restrict__ hb, float* __restrict__ si) {
  const int f32m = detect_f32((const u32*)h);
  const int wv = threadIdx.x >> 6, lane = threadIdx.x & 63;
  const int n = blockIdx.x * 4 + wv;
  uint4* hbrow = (uint4*)(hb + (size_t)n * INF_);          // 76 uint4 per row
  const float4* v4 = (const float4*)v;
  float sum = 0.f;
  if (f32m) {
    const float4* hr = (const float4*)((const float*)h + (size_t)n * INF_);
    for (int c = lane; c < 76; c += 64) {
      float4 x0 = hr[2 * c], x1 = hr[2 * c + 1];
      uint4 o;
      o.x = (u32)f2bf(x0.x) | ((u32)f2bf(x0.y) << 16);
      o.y = (u32)f2bf(x0.z) | ((u32)f2bf(x0.w) << 16);
      o.z = (u32)f2bf(x1.x) | ((u32)f2bf(x1.y) << 16);
      o.w = (u32)f2bf(x1.z) | ((u32)f2bf(x1.w) << 16);
      hbrow[c] = o;
      float4 w0 = v4[2 * c], w1 = v4[2 * c + 1];
      sum += x0.x * w0.x + x0.y * w0.y + x0.z * w0.z + x0.w * w0.w
           + x1.x * w1.x + x1.y * w1.y + x1.z * w1.z + x1.w * w1.w;
    }
  } else {
    const uint4* hr = (const uint4*)((const u16*)h + (size_t)n * INF_);
    for (int c = lane; c < 76; c += 64) {
      uint4 x = hr[c];
      hbrow[c] = x;
      float4 w0 = v4[2 * c], w1 = v4[2 * c + 1];
      sum += bflo(x.x) * w0.x + bfhi(x.x) * w0.y + bflo(x.y) * w0.z + bfhi(x.y) * w0.w
           + bflo(x.z) * w1.x + bfhi(x.z) * w1.y + bflo(x.w) * w1.z + bfhi(x.w) * w1.w;
    }
  }
#pragma unroll
  for (int o = 32; o; o >>= 1) sum += __shfl_xor(sum, o);
  if (lane == 0) si[n] = sum;
}

// ---- GEMM: Wh(bf16) = hb @ W_j, fused sj = Wh.a_j (fp32 acc, single path) ----
__global__ __launch_bounds__(256, 2) void gemm_kernel(
    const u16* __restrict__ A, const u16* __restrict__ Bt,
    u16* __restrict__ C, const float* __restrict__ ajf, float* __restrict__ sj) {
  __shared__ __align__(16) u16 As[128][32];
  __shared__ __align__(16) u16 Bs[128][32];
  const int tid  = threadIdx.x;
  const int lane = tid & 63;
  const int wave = tid >> 6;
  const int row0 = blockIdx.x * 128;
  const int col0 = blockIdx.y * 128;
  const int wm = (wave & 1) * 64;
  const int wn = (wave >> 1) * 64;

  f32x4 acc[4][4];
#pragma unroll
  for (int i = 0; i < 4; ++i)
#pragma unroll
    for (int j = 0; j < 4; ++j) acc[i][j] = (f32x4){0.f, 0.f, 0.f, 0.f};

  const int c0 = tid, c1 = tid + 256;              // 16B chunks 0..511
  const int rA0 = c0 >> 2, kc0 = (c0 & 3) * 16;
  const int rA1 = c1 >> 2, kc1 = (c1 & 3) * 16;
  const char* Ab  = (const char*)A;
  const char* Btb = (const char*)Bt;

  for (int kt = 0; kt < 19; ++kt) {
    const size_t kb = (size_t)kt * 64;             // 32 bf16 = 64 B of k
    async_ld16(Ab  + (size_t)(row0 + rA0) * 1216 + kb + kc0, (char*)As + c0 * 16);
    async_ld16(Ab  + (size_t)(row0 + rA1) * 1216 + kb + kc1, (char*)As + c1 * 16);
    async_ld16(Btb + (size_t)(col0 + rA0) * 1216 + kb + kc0, (char*)Bs + c0 * 16);
    async_ld16(Btb + (size_t)(col0 + rA1) * 1216 + kb + kc1, (char*)Bs + c1 * 16);
    __syncthreads();

    const int kk = (lane >> 4) * 8;
    const int lm0 = lane & 15;
    bf16x8 af[4], bfr[4];
#pragma unroll
    for (int i = 0; i < 4; ++i) af[i]  = *(const bf16x8*)&As[wm + i * 16 + lm0][kk];
#pragma unroll
    for (int i = 0; i < 4; ++i) bfr[i] = *(const bf16x8*)&Bs[wn + i * 16 + lm0][kk];
#pragma unroll
    for (int im = 0; im < 4; ++im)
#pragma unroll
      for (int in = 0; in < 4; ++in)
        acc[im][in] = __builtin_amdgcn_mfma_f32_16x16x32_bf16(
            af[im], bfr[in], acc[im][in], 0, 0, 0);
    __syncthreads();
  }

  const int lm = lane & 15, lq = lane >> 4;
#pragma unroll
  for (int im = 0; im < 4; ++im)
#pragma unroll
    for (int in = 0; in < 4; ++in) {
      const int colg = col0 + wn + in * 16 + lm;
#pragma unroll
      for (int r = 0; r < 4; ++r) {
        const int rowg = row0 + wm + im * 16 + lq * 4 + r;
        C[(size_t)rowg * HID_ + colg] = f2bf(acc[im][in][r]);
      }
    }
  // fused sj epilogue
  float ajv[4];
#pragma unroll
  for (int in = 0; in < 4; ++in) ajv[in] = ajf[col0 + wn + in * 16 + lm];
#pragma unroll
  for (int im = 0; im < 4; ++im)
#pragma unroll
    for (int r = 0; r < 4; ++r) {
      float p = acc[im][0][r] * ajv[0] + acc[im][1][r] * ajv[1]
              + acc[im][2][r] * ajv[2] + acc[im][3][r] * ajv[3];
      p += __shfl_xor(p, 1); p += __shfl_xor(p, 2);
      p += __shfl_xor(p, 4); p += __shfl_xor(p, 8);
      if (lm == 0) atomicAdd(&sj[row0 + wm + im * 16 + lq * 4 + r], p);
    }
}

// ---- attn: scores + softmax (shfl) + latency-batched gather (r5 shape).
// Gather is latency-bound (r5: 2.7 TB/s eff, r6 post-mortem): issue 8 uint4
// loads back-to-back per batch so each wave exposes 4 latency windows per row
// instead of ~25. Invalid k's load row 0 with w=0 (no branch in the loop).
__global__ __launch_bounds__(256) void attn_kernel(
    const void* __restrict__ h, const int* __restrict__ ci,
    const float* __restrict__ si, const float* __restrict__ sj,
    const float* __restrict__ abf, const u16* __restrict__ Wh,
    void* __restrict__ out) {
  const int f32m = detect_f32((const u32*)h);
  const int i64  = detect_i64(ci);
  const int wv = threadIdx.x >> 6, lane = threadIdx.x & 63;
  const int n = blockIdx.x * 4 + wv;

  float att = 0.f; int idxv = 0;
  if (lane < 32) {
    const size_t t = (size_t)n * KCTX + lane;
    int idx;
    if (i64) { int lo = ci[2 * t], hi = ci[2 * t + 1]; idx = (hi < 0) ? -1 : lo; }
    else     { idx = ci[t]; }
    const bool valid = idx >= 0;
    const float sjv = valid ? sj[idx] : 0.f;
    float raw = si[n] + sjv + abf[0];
    float lr = raw > 0.f ? raw : 0.2f * raw;
    float s = valid ? lr : -9e15f;
    float m = s;
#pragma unroll
    for (int o = 16; o; o >>= 1) m = fmaxf(m, __shfl_xor(m, o, 32));
    float p = __expf(s - m);
    float d = p;
#pragma unroll
    for (int o = 16; o; o >>= 1) d += __shfl_xor(d, o, 32);
    att = valid ? p / d : 0.f;
    idxv = valid ? idx : 0;                        // invalid -> row 0, w = 0
  }

  if (lane < 48) {
    float a0 = 0, a1 = 0, a2 = 0, a3 = 0, a4 = 0, a5 = 0, a6 = 0, a7 = 0;
#pragma unroll
    for (int kb = 0; kb < KCTX; kb += 8) {
      uint4 q[8]; float ww[8];
#pragma unroll
      for (int u = 0; u < 8; ++u) {                // 8 loads in flight
        ww[u] = __shfl(att, kb + u);
        const int j = __shfl(idxv, kb + u);
        q[u] = ((const uint4*)(Wh + (u32)j * HID_))[lane];
      }
#pragma unroll
      for (int u = 0; u < 8; ++u) {
        const float w = ww[u];
        a0 += w * bflo(q[u].x); a1 += w * bfhi(q[u].x);
        a2 += w * bflo(q[u].y); a3 += w * bfhi(q[u].y);
        a4 += w * bflo(q[u].z); a5 += w * bfhi(q[u].z);
        a6 += w * bflo(q[u].w); a7 += w * bfhi(q[u].w);
      }
    }
    if (f32m) {
      float4* o4 = (float4*)out + (size_t)n * 96 + lane * 2;
      o4[0] = (float4){a0, a1, a2, a3};
      o4[1] = (float4){a4, a5, a6, a7};
    } else {
      uint4 o;
      o.x = (u32)f2bf(a0) | ((u32)f2bf(a1) << 16);
      o.y = (u32)f2bf(a2) | ((u32)f2bf(a3) << 16);
      o.z = (u32)f2bf(a4) | ((u32)f2bf(a5) << 16);
      o.w = (u32)f2bf(a6) | ((u32)f2bf(a7) << 16);
      ((uint4*)out)[(size_t)n * 48 + lane] = o;
    }
  }
}

extern "C" void kernel_launch(void* const* d_in, const int* in_sizes, int n_in,
                              void* d_out, int out_size, void* d_ws, size_t ws_size,
                              hipStream_t stream) {
  const void* h  = d_in[0];
  const int*  ci = (const int*)d_in[1];
  const void* Wi = d_in[2];
  const void* Wj = d_in[3];
  const void* ai = d_in[4];
  const void* aj = d_in[5];
  const void* ab = d_in[6];

  char* ws = (char*)d_ws;
  u16*   hb  = (u16*)(ws + HB_OFF);
  u16*   Wh  = (u16*)(ws + WH_OFF);
  u16*   Bt  = (u16*)(ws + BT_OFF);
  float* v   = (float*)(ws + V_OFF);
  float* si  = (float*)(ws + SI_OFF);
  float* sj  = (float*)(ws + SJ_OFF);
  float* ajf = (float*)(ws + AJF_OFF);
  float* abf = (float*)(ws + ABF_OFF);

  prep_kernel<<<99, 256, 0, stream>>>(h, Wi, Wj, ai, aj, ab, Bt, v, sj, ajf, abf);
  conv_kernel<<<4096, 256, 0, stream>>>(h, v, hb, si);
  dim3 g(128, 3);
  gemm_kernel<<<g, 256, 0, stream>>>(hb, Bt, Wh, ajf, sj);
  attn_kernel<<<4096, 256, 0, stream>>>(h, ci, si, sj, abf, Wh, d_out);
}

// Round 8
// 156.687 us; speedup vs baseline: 1.3926x; 1.0249x over previous
//
#include <hip/hip_runtime.h>
#include <hip/hip_bf16.h>

typedef unsigned short u16;
typedef unsigned int u32;
typedef __attribute__((ext_vector_type(8))) __bf16 bf16x8;
typedef __attribute__((ext_vector_type(4))) __bf16 bf16x4;
typedef __attribute__((ext_vector_type(4))) float f32x4;

#define KCTX 32
#define INF_ 608
#define HID_ 384

// ws layout (bytes). (hb region retired in r8; offsets kept stable.)
#define WH_OFF  19922944              // Wh  [16384,384] bf16 = 12,582,912
#define BT_OFF  32505856              // Bt  [384,608]  bf16 =    466,944
#define V_OFF   32972800              // v   [608] f32        =      2,432
#define SI_OFF  32975232              // si  [16384] f32      =     65,536
#define SJ_OFF  33040768              // sj  [16384] f32      =     65,536
#define AJF_OFF 33106304              // ajf [384] f32        =      1,536
#define ABF_OFF 33107840              // abf [1] f32

__device__ __forceinline__ float bfu(u16 u)  { return __uint_as_float(((u32)u) << 16); }
__device__ __forceinline__ float bflo(u32 u) { return __uint_as_float(u << 16); }
__device__ __forceinline__ float bfhi(u32 u) { return __uint_as_float(u & 0xffff0000u); }
__device__ __forceinline__ u16 f2bf(float x) {            // round-to-nearest-even
  u32 u = __float_as_uint(x);
  return (u16)((u + 0x7fffu + ((u >> 16) & 1u)) >> 16);
}
__device__ __forceinline__ void async_ld16(const void* g, void* l) {
  __builtin_amdgcn_global_load_lds(
      (const __attribute__((address_space(1))) u32*)g,
      (__attribute__((address_space(3))) u32*)l, 16, 0, 0);
}

// ---- per-wave runtime dtype detection (wave-uniform, L2-hot; validated r2-r7) ----
__device__ __forceinline__ int detect_f32(const u32* hw) {
  const u32 w = hw[threadIdx.x & 63];
  const int e = (int)((w >> 7) & 0xffu);
  const unsigned long long mb = __ballot(e > 134 || e < 100);
  return __popcll(mb) >= 16;
}
__device__ __forceinline__ int detect_i64(const int* ci) {
  const int hi = ci[2 * (threadIdx.x & 63) + 1];
  const unsigned long long mz = __ballot(hi == 0 || hi == -1);
  return __popcll(mz) >= 48;
}

// ---- prep: Bt = bf16(W_j^T), v = W_i@a_i, ajf/abf fp32, zero sj ----
__global__ __launch_bounds__(256) void prep_kernel(
    const void* __restrict__ h, const void* __restrict__ Wi,
    const void* __restrict__ Wj, const void* __restrict__ ai,
    const void* __restrict__ aj, const void* __restrict__ ab,
    u16* __restrict__ Bt, float* __restrict__ v, float* __restrict__ sj,
    float* __restrict__ ajf, float* __restrict__ abf) {
  __shared__ u16 tile[64][65];
  const int f32m = detect_f32((const u32*)h);
  const int bid = blockIdx.x, tid = threadIdx.x;
  if (bid < 60) {                                  // transpose: 10(f) x 6(h) tiles
    const int ft = bid / 6, ht = bid - ft * 6;
    const int f0 = ft * 64, h0 = ht * 64;
    const int ln = tid & 63, fg = tid >> 6;
#pragma unroll
    for (int rr = 0; rr < 16; ++rr) {              // read: lanes contiguous in h
      const int fl = fg * 16 + rr;
      const int f = f0 + fl;
      if (f < INF_)
        tile[fl][ln] = f32m ? f2bf(((const float*)Wj)[(size_t)f * HID_ + h0 + ln])
                            : ((const u16*)Wj)[(size_t)f * HID_ + h0 + ln];
    }
    __syncthreads();
#pragma unroll
    for (int rr = 0; rr < 16; ++rr) {              // write: lanes contiguous in f
      const int hl = fg * 16 + rr;
      const int f = f0 + ln;
      if (f < INF_) Bt[(size_t)(h0 + hl) * INF_ + f] = tile[ln][hl];
    }
  } else if (bid < 98) {                           // v: 16-lane group per row
    const int t = (bid - 60) * 16 + (tid >> 4);    // row 0..607
    const int sl = tid & 15;
    if (t < INF_) {
      float s = 0.f;
      if (f32m) {
        const float4* wi = (const float4*)((const float*)Wi + (size_t)t * HID_);
        const float4* a4 = (const float4*)ai;
        for (int c = sl; c < 96; c += 16) {
          float4 x = wi[c], y = a4[c];
          s += x.x * y.x + x.y * y.y + x.z * y.z + x.w * y.w;
        }
      } else {
        const uint4* wi = (const uint4*)((const u16*)Wi + (size_t)t * HID_);
        const uint4* a4 = (const uint4*)ai;
        for (int c = sl; c < 48; c += 16) {
          uint4 x = wi[c], y = a4[c];
          s += bflo(x.x) * bflo(y.x) + bfhi(x.x) * bfhi(y.x)
             + bflo(x.y) * bflo(y.y) + bfhi(x.y) * bfhi(y.y)
             + bflo(x.z) * bflo(y.z) + bfhi(x.z) * bfhi(y.z)
             + bflo(x.w) * bflo(y.w) + bfhi(x.w) * bfhi(y.w);
        }
      }
      s += __shfl_xor(s, 1); s += __shfl_xor(s, 2);
      s += __shfl_xor(s, 4); s += __shfl_xor(s, 8);
      if (sl == 0) v[t] = s;
    }
  } else {                                         // zero sj, build ajf/abf
#pragma unroll 8
    for (int j = 0; j < 64; ++j) sj[j * 256 + tid] = 0.f;
    for (int j = tid; j < HID_; j += 256)
      ajf[j] = f32m ? ((const float*)aj)[j] : bfu(((const u16*)aj)[j]);
    if (tid == 0)
      abf[0] = f32m ? ((const float*)ab)[0] : bfu(((const u16*)ab)[0]);
  }
}

// ---- gemm_fused: per block, 32 rows A-resident in LDS (h read ONCE, fp32->bf16
// convert inline, fp32-exact si fused), Bt streamed 32-k chunks via
// global_load_lds, 4 waves x (m=32,n=96) MFMA, fused sj epilogue.
// LDS = 39168 (As, +4 pad -> 4-way a-frag banking) + 24576 (Bs) = 63744 B.
__global__ __launch_bounds__(256) void gemm_fused(
    const void* __restrict__ A,     // h [16384,608] fp32 or bf16
    const u16* __restrict__ Bt,     // [384,608] bf16
    const float* __restrict__ v,
    u16* __restrict__ C,            // Wh [16384,384] bf16
    float* __restrict__ si, const float* __restrict__ ajf,
    float* __restrict__ sj) {
  __shared__ __align__(16) u16 As[32][612];
  __shared__ __align__(16) u16 Bs[12288];          // [384][32]
  const int f32m = detect_f32((const u32*)A);
  const int tid  = threadIdx.x;
  const int lane = tid & 63;
  const int wv   = tid >> 6;                       // 0..3
  const int row0 = blockIdx.x * 32;
  const char* Btb = (const char*)Bt;

  // stage chunk 0 early (DMA overlaps phase-1 conversion)
#pragma unroll
  for (int i = 0; i < 6; ++i) {
    const int c = tid + i * 256;                   // 0..1535
    async_ld16(Btb + (size_t)(c >> 2) * 1216 + (c & 3) * 16, (char*)Bs + c * 16);
  }

  // ---- phase 1: A load+convert+si (8 threads per row) ----
  {
    const int g = tid >> 3, sub = tid & 7;         // row 0..31 in block
    float s = 0.f;
    const float4* v4 = (const float4*)v;
    if (f32m) {
      const float4* hr = (const float4*)((const float*)A + (size_t)(row0 + g) * INF_);
#pragma unroll
      for (int k = 0; k < 19; ++k) {
        const int c4 = sub + 8 * k;                // 0..151
        float4 x = hr[c4];
        ushort4 sv;
        sv.x = f2bf(x.x); sv.y = f2bf(x.y); sv.z = f2bf(x.z); sv.w = f2bf(x.w);
        *(ushort4*)&As[g][c4 * 4] = sv;
        float4 w = v4[c4];
        s += x.x * w.x + x.y * w.y + x.z * w.z + x.w * w.w;
      }
    } else {
      const uint4* hr = (const uint4*)((const u16*)A + (size_t)(row0 + g) * INF_);
      for (int k = 0; k < 10; ++k) {
        const int c8 = sub + 8 * k;                // 0..75
        if (c8 < 76) {
          uint4 x = hr[c8];
          *(ushort4*)&As[g][c8 * 8]     = *(ushort4*)&x.x;   // 8 B (row base is 8-B aligned)
          *(ushort4*)&As[g][c8 * 8 + 4] = *(ushort4*)&x.z;
          float4 w0 = v4[2 * c8], w1 = v4[2 * c8 + 1];
          s += bflo(x.x) * w0.x + bfhi(x.x) * w0.y + bflo(x.y) * w0.z + bfhi(x.y) * w0.w
             + bflo(x.z) * w1.x + bfhi(x.z) * w1.y + bflo(x.w) * w1.z + bfhi(x.w) * w1.w;
        }
      }
    }
    s += __shfl_xor(s, 1); s += __shfl_xor(s, 2); s += __shfl_xor(s, 4);
    if (sub == 0) si[row0 + g] = s;
  }

  // ---- phase 2: K-loop ----
  f32x4 acc[2][6];
#pragma unroll
  for (int i = 0; i < 2; ++i)
#pragma unroll
    for (int j = 0; j < 6; ++j) acc[i][j] = (f32x4){0.f, 0.f, 0.f, 0.f};

  const int lm = lane & 15, q = lane >> 4;
  const int n0 = wv * 96;

  for (int kt = 0; kt < 19; ++kt) {
    __syncthreads();                               // drains staging of chunk kt
    bf16x8 af[2], bfr[6];
#pragma unroll
    for (int im = 0; im < 2; ++im) {
      const int r = im * 16 + lm;
      bf16x4 lo = *(const bf16x4*)&As[r][kt * 32 + q * 8];
      bf16x4 hi = *(const bf16x4*)&As[r][kt * 32 + q * 8 + 4];
      af[im] = __builtin_shufflevector(lo, hi, 0, 1, 2, 3, 4, 5, 6, 7);
    }
#pragma unroll
    for (int in = 0; in < 6; ++in)
      bfr[in] = *(const bf16x8*)&Bs[(n0 + in * 16 + lm) * 32 + q * 8];
#pragma unroll
    for (int im = 0; im < 2; ++im)
#pragma unroll
      for (int in = 0; in < 6; ++in)
        acc[im][in] = __builtin_amdgcn_mfma_f32_16x16x32_bf16(
            af[im], bfr[in], acc[im][in], 0, 0, 0);
    __syncthreads();                               // all reads of Bs done
    if (kt < 18) {
      const size_t kb = (size_t)(kt + 1) * 64;
#pragma unroll
      for (int i = 0; i < 6; ++i) {
        const int c = tid + i * 256;
        async_ld16(Btb + (size_t)(c >> 2) * 1216 + kb + (c & 3) * 16, (char*)Bs + c * 16);
      }
    }
  }

  // ---- epilogue: C store + fused sj ----
#pragma unroll
  for (int im = 0; im < 2; ++im)
#pragma unroll
    for (int in = 0; in < 6; ++in) {
      const int colg = n0 + in * 16 + lm;
#pragma unroll
      for (int r = 0; r < 4; ++r) {
        const int rowg = row0 + im * 16 + q * 4 + r;
        C[(size_t)rowg * HID_ + colg] = f2bf(acc[im][in][r]);
      }
    }
  float ajv[6];
#pragma unroll
  for (int in = 0; in < 6; ++in) ajv[in] = ajf[n0 + in * 16 + lm];
#pragma unroll
  for (int im = 0; im < 2; ++im)
#pragma unroll
    for (int r = 0; r < 4; ++r) {
      float p = acc[im][0][r] * ajv[0] + acc[im][1][r] * ajv[1]
              + acc[im][2][r] * ajv[2] + acc[im][3][r] * ajv[3]
              + acc[im][4][r] * ajv[4] + acc[im][5][r] * ajv[5];
      p += __shfl_xor(p, 1); p += __shfl_xor(p, 2);
      p += __shfl_xor(p, 4); p += __shfl_xor(p, 8);
      if (lm == 0) atomicAdd(&sj[row0 + im * 16 + q * 4 + r], p);
    }
}

// ---- attn: scores + softmax (shfl) + latency-batched gather (r7, unchanged) ----
__global__ __launch_bounds__(256) void attn_kernel(
    const void* __restrict__ h, const int* __restrict__ ci,
    const float* __restrict__ si, const float* __restrict__ sj,
    const float* __restrict__ abf, const u16* __restrict__ Wh,
    void* __restrict__ out) {
  const int f32m = detect_f32((const u32*)h);
  const int i64  = detect_i64(ci);
  const int wv = threadIdx.x >> 6, lane = threadIdx.x & 63;
  const int n = blockIdx.x * 4 + wv;

  float att = 0.f; int idxv = 0;
  if (lane < 32) {
    const size_t t = (size_t)n * KCTX + lane;
    int idx;
    if (i64) { int lo = ci[2 * t], hi = ci[2 * t + 1]; idx = (hi < 0) ? -1 : lo; }
    else     { idx = ci[t]; }
    const bool valid = idx >= 0;
    const float sjv = valid ? sj[idx] : 0.f;
    float raw = si[n] + sjv + abf[0];
    float lr = raw > 0.f ? raw : 0.2f * raw;
    float s = valid ? lr : -9e15f;
    float m = s;
#pragma unroll
    for (int o = 16; o; o >>= 1) m = fmaxf(m, __shfl_xor(m, o, 32));
    float p = __expf(s - m);
    float d = p;
#pragma unroll
    for (int o = 16; o; o >>= 1) d += __shfl_xor(d, o, 32);
    att = valid ? p / d : 0.f;
    idxv = valid ? idx : 0;                        // invalid -> row 0, w = 0
  }

  if (lane < 48) {
    float a0 = 0, a1 = 0, a2 = 0, a3 = 0, a4 = 0, a5 = 0, a6 = 0, a7 = 0;
#pragma unroll
    for (int kb = 0; kb < KCTX; kb += 8) {
      uint4 q[8]; float ww[8];
#pragma unroll
      for (int u = 0; u < 8; ++u) {                // 8 loads in flight
        ww[u] = __shfl(att, kb + u);
        const int j = __shfl(idxv, kb + u);
        q[u] = ((const uint4*)(Wh + (u32)j * HID_))[lane];
      }
#pragma unroll
      for (int u = 0; u < 8; ++u) {
        const float w = ww[u];
        a0 += w * bflo(q[u].x); a1 += w * bfhi(q[u].x);
        a2 += w * bflo(q[u].y); a3 += w * bfhi(q[u].y);
        a4 += w * bflo(q[u].z); a5 += w * bfhi(q[u].z);
        a6 += w * bflo(q[u].w); a7 += w * bfhi(q[u].w);
      }
    }
    if (f32m) {
      float4* o4 = (float4*)out + (size_t)n * 96 + lane * 2;
      o4[0] = (float4){a0, a1, a2, a3};
      o4[1] = (float4){a4, a5, a6, a7};
    } else {
      uint4 o;
      o.x = (u32)f2bf(a0) | ((u32)f2bf(a1) << 16);
      o.y = (u32)f2bf(a2) | ((u32)f2bf(a3) << 16);
      o.z = (u32)f2bf(a4) | ((u32)f2bf(a5) << 16);
      o.w = (u32)f2bf(a6) | ((u32)f2bf(a7) << 16);
      ((uint4*)out)[(size_t)n * 48 + lane] = o;
    }
  }
}

extern "C" void kernel_launch(void* const* d_in, const int* in_sizes, int n_in,
                              void* d_out, int out_size, void* d_ws, size_t ws_size,
                              hipStream_t stream) {
  const void* h  = d_in[0];
  const int*  ci = (const int*)d_in[1];
  const void* Wi = d_in[2];
  const void* Wj = d_in[3];
  const void* ai = d_in[4];
  const void* aj = d_in[5];
  const void* ab = d_in[6];

  char* ws = (char*)d_ws;
  u16*   Wh  = (u16*)(ws + WH_OFF);
  u16*   Bt  = (u16*)(ws + BT_OFF);
  float* v   = (float*)(ws + V_OFF);
  float* si  = (float*)(ws + SI_OFF);
  float* sj  = (float*)(ws + SJ_OFF);
  float* ajf = (float*)(ws + AJF_OFF);
  float* abf = (float*)(ws + ABF_OFF);

  prep_kernel<<<99, 256, 0, stream>>>(h, Wi, Wj, ai, aj, ab, Bt, v, sj, ajf, abf);
  gemm_fused<<<512, 256, 0, stream>>>(h, Bt, v, Wh, si, ajf, sj);
  attn_kernel<<<4096, 256, 0, stream>>>(h, ci, si, sj, abf, Wh, d_out);
}

// Round 9
// 156.408 us; speedup vs baseline: 1.3951x; 1.0018x over previous
//
#include <hip/hip_runtime.h>
#include <hip/hip_bf16.h>

typedef unsigned short u16;
typedef unsigned int u32;
typedef __attribute__((ext_vector_type(8))) __bf16 bf16x8;
typedef __attribute__((ext_vector_type(4))) __bf16 bf16x4;
typedef __attribute__((ext_vector_type(4))) float f32x4;

#define KCTX 32
#define INF_ 608
#define HID_ 384
#define NBOX 16384

// ws layout (bytes).
#define WH_OFF  19922944              // Wh  [16384,384] bf16 = 12,582,912
#define BT_OFF  32505856              // Bt  [384,608]  bf16 =    466,944
#define V_OFF   32972800              // v   [608] f32        =      2,432
#define SI_OFF  32975232              // si  [16384] f32      =     65,536
#define SJ_OFF  33040768              // sj  [16384] f32      =     65,536
#define AJF_OFF 33106304              // ajf [384] f32        =      1,536
#define ABF_OFF 33107840              // abf [1] f32

__device__ __forceinline__ float bfu(u16 u)  { return __uint_as_float(((u32)u) << 16); }
__device__ __forceinline__ float bflo(u32 u) { return __uint_as_float(u << 16); }
__device__ __forceinline__ float bfhi(u32 u) { return __uint_as_float(u & 0xffff0000u); }
__device__ __forceinline__ u16 f2bf(float x) {            // round-to-nearest-even
  u32 u = __float_as_uint(x);
  return (u16)((u + 0x7fffu + ((u >> 16) & 1u)) >> 16);
}
__device__ __forceinline__ void async_ld16(const void* g, void* l) {
  __builtin_amdgcn_global_load_lds(
      (const __attribute__((address_space(1))) u32*)g,
      (__attribute__((address_space(3))) u32*)l, 16, 0, 0);
}

// ---- per-wave runtime dtype detection (wave-uniform, L2-hot; validated r2-r8) ----
__device__ __forceinline__ int detect_f32(const u32* hw) {
  const u32 w = hw[threadIdx.x & 63];
  const int e = (int)((w >> 7) & 0xffu);
  const unsigned long long mb = __ballot(e > 134 || e < 100);
  return __popcll(mb) >= 16;
}
__device__ __forceinline__ int detect_i64(const int* ci) {
  const int hi = ci[2 * (threadIdx.x & 63) + 1];
  const unsigned long long mz = __ballot(hi == 0 || hi == -1);
  return __popcll(mz) >= 48;
}

// ---- prep: Bt = bf16(W_j^T), v = W_i@a_i, ajf/abf fp32, zero sj (r8, unchanged) ----
__global__ __launch_bounds__(256) void prep_kernel(
    const void* __restrict__ h, const void* __restrict__ Wi,
    const void* __restrict__ Wj, const void* __restrict__ ai,
    const void* __restrict__ aj, const void* __restrict__ ab,
    u16* __restrict__ Bt, float* __restrict__ v, float* __restrict__ sj,
    float* __restrict__ ajf, float* __restrict__ abf) {
  __shared__ u16 tile[64][65];
  const int f32m = detect_f32((const u32*)h);
  const int bid = blockIdx.x, tid = threadIdx.x;
  if (bid < 60) {                                  // transpose: 10(f) x 6(h) tiles
    const int ft = bid / 6, ht = bid - ft * 6;
    const int f0 = ft * 64, h0 = ht * 64;
    const int ln = tid & 63, fg = tid >> 6;
#pragma unroll
    for (int rr = 0; rr < 16; ++rr) {
      const int fl = fg * 16 + rr;
      const int f = f0 + fl;
      if (f < INF_)
        tile[fl][ln] = f32m ? f2bf(((const float*)Wj)[(size_t)f * HID_ + h0 + ln])
                            : ((const u16*)Wj)[(size_t)f * HID_ + h0 + ln];
    }
    __syncthreads();
#pragma unroll
    for (int rr = 0; rr < 16; ++rr) {
      const int hl = fg * 16 + rr;
      const int f = f0 + ln;
      if (f < INF_) Bt[(size_t)(h0 + hl) * INF_ + f] = tile[ln][hl];
    }
  } else if (bid < 98) {                           // v: 16-lane group per row
    const int t = (bid - 60) * 16 + (tid >> 4);
    const int sl = tid & 15;
    if (t < INF_) {
      float s = 0.f;
      if (f32m) {
        const float4* wi = (const float4*)((const float*)Wi + (size_t)t * HID_);
        const float4* a4 = (const float4*)ai;
        for (int c = sl; c < 96; c += 16) {
          float4 x = wi[c], y = a4[c];
          s += x.x * y.x + x.y * y.y + x.z * y.z + x.w * y.w;
        }
      } else {
        const uint4* wi = (const uint4*)((const u16*)Wi + (size_t)t * HID_);
        const uint4* a4 = (const uint4*)ai;
        for (int c = sl; c < 48; c += 16) {
          uint4 x = wi[c], y = a4[c];
          s += bflo(x.x) * bflo(y.x) + bfhi(x.x) * bfhi(y.x)
             + bflo(x.y) * bflo(y.y) + bfhi(x.y) * bfhi(y.y)
             + bflo(x.z) * bflo(y.z) + bfhi(x.z) * bfhi(y.z)
             + bflo(x.w) * bflo(y.w) + bfhi(x.w) * bfhi(y.w);
        }
      }
      s += __shfl_xor(s, 1); s += __shfl_xor(s, 2);
      s += __shfl_xor(s, 4); s += __shfl_xor(s, 8);
      if (sl == 0) v[t] = s;
    }
  } else {                                         // zero sj, build ajf/abf
#pragma unroll 8
    for (int j = 0; j < 64; ++j) sj[j * 256 + tid] = 0.f;
    for (int j = tid; j < HID_; j += 256)
      ajf[j] = f32m ? ((const float*)aj)[j] : bfu(((const u16*)aj)[j]);
    if (tid == 0)
      abf[0] = f32m ? ((const float*)ab)[0] : bfu(((const u16*)ab)[0]);
  }
}

// ---- gemm_fused (r8, unchanged): 32 rows A-resident, Bt streamed, si+sj fused ----
__global__ __launch_bounds__(256) void gemm_fused(
    const void* __restrict__ A, const u16* __restrict__ Bt,
    const float* __restrict__ v, u16* __restrict__ C,
    float* __restrict__ si, const float* __restrict__ ajf,
    float* __restrict__ sj) {
  __shared__ __align__(16) u16 As[32][612];
  __shared__ __align__(16) u16 Bs[12288];          // [384][32]
  const int f32m = detect_f32((const u32*)A);
  const int tid  = threadIdx.x;
  const int lane = tid & 63;
  const int wv   = tid >> 6;
  const int row0 = blockIdx.x * 32;
  const char* Btb = (const char*)Bt;

#pragma unroll
  for (int i = 0; i < 6; ++i) {
    const int c = tid + i * 256;
    async_ld16(Btb + (size_t)(c >> 2) * 1216 + (c & 3) * 16, (char*)Bs + c * 16);
  }

  {
    const int g = tid >> 3, sub = tid & 7;
    float s = 0.f;
    const float4* v4 = (const float4*)v;
    if (f32m) {
      const float4* hr = (const float4*)((const float*)A + (size_t)(row0 + g) * INF_);
#pragma unroll
      for (int k = 0; k < 19; ++k) {
        const int c4 = sub + 8 * k;
        float4 x = hr[c4];
        ushort4 sv;
        sv.x = f2bf(x.x); sv.y = f2bf(x.y); sv.z = f2bf(x.z); sv.w = f2bf(x.w);
        *(ushort4*)&As[g][c4 * 4] = sv;
        float4 w = v4[c4];
        s += x.x * w.x + x.y * w.y + x.z * w.z + x.w * w.w;
      }
    } else {
      const uint4* hr = (const uint4*)((const u16*)A + (size_t)(row0 + g) * INF_);
      for (int k = 0; k < 10; ++k) {
        const int c8 = sub + 8 * k;
        if (c8 < 76) {
          uint4 x = hr[c8];
          *(ushort4*)&As[g][c8 * 8]     = *(ushort4*)&x.x;
          *(ushort4*)&As[g][c8 * 8 + 4] = *(ushort4*)&x.z;
          float4 w0 = v4[2 * c8], w1 = v4[2 * c8 + 1];
          s += bflo(x.x) * w0.x + bfhi(x.x) * w0.y + bflo(x.y) * w0.z + bfhi(x.y) * w0.w
             + bflo(x.z) * w1.x + bfhi(x.z) * w1.y + bflo(x.w) * w1.z + bfhi(x.w) * w1.w;
        }
      }
    }
    s += __shfl_xor(s, 1); s += __shfl_xor(s, 2); s += __shfl_xor(s, 4);
    if (sub == 0) si[row0 + g] = s;
  }

  f32x4 acc[2][6];
#pragma unroll
  for (int i = 0; i < 2; ++i)
#pragma unroll
    for (int j = 0; j < 6; ++j) acc[i][j] = (f32x4){0.f, 0.f, 0.f, 0.f};

  const int lm = lane & 15, q = lane >> 4;
  const int n0 = wv * 96;

  for (int kt = 0; kt < 19; ++kt) {
    __syncthreads();
    bf16x8 af[2], bfr[6];
#pragma unroll
    for (int im = 0; im < 2; ++im) {
      const int r = im * 16 + lm;
      bf16x4 lo = *(const bf16x4*)&As[r][kt * 32 + q * 8];
      bf16x4 hi = *(const bf16x4*)&As[r][kt * 32 + q * 8 + 4];
      af[im] = __builtin_shufflevector(lo, hi, 0, 1, 2, 3, 4, 5, 6, 7);
    }
#pragma unroll
    for (int in = 0; in < 6; ++in)
      bfr[in] = *(const bf16x8*)&Bs[(n0 + in * 16 + lm) * 32 + q * 8];
#pragma unroll
    for (int im = 0; im < 2; ++im)
#pragma unroll
      for (int in = 0; in < 6; ++in)
        acc[im][in] = __builtin_amdgcn_mfma_f32_16x16x32_bf16(
            af[im], bfr[in], acc[im][in], 0, 0, 0);
    __syncthreads();
    if (kt < 18) {
      const size_t kb = (size_t)(kt + 1) * 64;
#pragma unroll
      for (int i = 0; i < 6; ++i) {
        const int c = tid + i * 256;
        async_ld16(Btb + (size_t)(c >> 2) * 1216 + kb + (c & 3) * 16, (char*)Bs + c * 16);
      }
    }
  }

#pragma unroll
  for (int im = 0; im < 2; ++im)
#pragma unroll
    for (int in = 0; in < 6; ++in) {
      const int colg = n0 + in * 16 + lm;
#pragma unroll
      for (int r = 0; r < 4; ++r) {
        const int rowg = row0 + im * 16 + q * 4 + r;
        C[(size_t)rowg * HID_ + colg] = f2bf(acc[im][in][r]);
      }
    }
  float ajv[6];
#pragma unroll
  for (int in = 0; in < 6; ++in) ajv[in] = ajf[n0 + in * 16 + lm];
#pragma unroll
  for (int im = 0; im < 2; ++im)
#pragma unroll
    for (int r = 0; r < 4; ++r) {
      float p = acc[im][0][r] * ajv[0] + acc[im][1][r] * ajv[1]
              + acc[im][2][r] * ajv[2] + acc[im][3][r] * ajv[3]
              + acc[im][4][r] * ajv[4] + acc[im][5][r] * ajv[5];
      p += __shfl_xor(p, 1); p += __shfl_xor(p, 2);
      p += __shfl_xor(p, 4); p += __shfl_xor(p, 8);
      if (lm == 0) atomicAdd(&sj[row0 + im * 16 + q * 4 + r], p);
    }
}

// ---- attn: 5 rows/block, compacted valid-k gather, 8-deep batching ----
// Score phase: t = r*32+k (32-groups wave-aligned, shfl softmax), compaction
// via ballot+prefix into packed float2 (att, idx) LDS slots, padded to x8.
// Gather phase: t = r*48+c, 240/256 lanes active, uint4 per (row,k).
__global__ __launch_bounds__(256) void attn_kernel(
    const void* __restrict__ h, const int* __restrict__ ci,
    const float* __restrict__ si, const float* __restrict__ sj,
    const float* __restrict__ abf, const u16* __restrict__ Wh,
    void* __restrict__ out) {
  __shared__ float2 ai_c[5][32];     // .x = att weight, .y = idx bits
  __shared__ int cnt_s[5];
  const int f32m = detect_f32((const u32*)h);
  const int i64  = detect_i64(ci);
  const int tid = threadIdx.x;
  const int n0 = blockIdx.x * 5;

  if (tid < 160) {
    const int r = tid >> 5, k = tid & 31;
    const int n = n0 + r;
    if (n < NBOX) {
      const size_t t = (size_t)n * KCTX + k;
      int idx;
      if (i64) { int lo = ci[2 * t], hi2 = ci[2 * t + 1]; idx = (hi2 < 0) ? -1 : lo; }
      else     { idx = ci[t]; }
      const bool valid = idx >= 0;
      const float sjv = valid ? sj[idx] : 0.f;
      float raw = si[n] + sjv + abf[0];
      float lr = raw > 0.f ? raw : 0.2f * raw;
      float s = valid ? lr : -9e15f;
      float m = s;
#pragma unroll
      for (int o = 16; o; o >>= 1) m = fmaxf(m, __shfl_xor(m, o, 32));
      float p = __expf(s - m);
      float d = p;
#pragma unroll
      for (int o = 16; o; o >>= 1) d += __shfl_xor(d, o, 32);
      // compact valid entries to the front of ai_c[r]
      const unsigned long long bm = __ballot(valid);
      const u32 m32 = (u32)(bm >> (tid & 32));     // this 32-group's mask
      const int cnt = __popc(m32);
      const int r8 = (cnt + 7) & ~7;               // pad to multiple of 8
      if (valid) {
        const int pf = __popc(m32 & ((1u << k) - 1u));
        ai_c[r][pf] = (float2){p / d, __int_as_float(idx)};
      }
      if (k >= cnt && k < r8) ai_c[r][k] = (float2){0.f, 0.f};  // pad: w=0, idx=0
      if (k == 0) cnt_s[r] = r8;
    } else if ((tid & 31) == 0) {
      cnt_s[r] = 0;
    }
  }
  __syncthreads();

  if (tid < 240) {
    const int r = tid / 48, c = tid - r * 48;
    const int n = n0 + r;
    if (n < NBOX) {
      const int K8 = cnt_s[r];
      float a0 = 0, a1 = 0, a2 = 0, a3 = 0, a4 = 0, a5 = 0, a6 = 0, a7 = 0;
      for (int kb = 0; kb < K8; kb += 8) {
        uint4 q[8]; float ww[8];
#pragma unroll
        for (int u = 0; u < 8; ++u) {              // 8 loads in flight
          const float2 e = ai_c[r][kb + u];
          ww[u] = e.x;
          const int j = __float_as_int(e.y);
          q[u] = ((const uint4*)(Wh + (u32)j * HID_))[c];
        }
#pragma unroll
        for (int u = 0; u < 8; ++u) {
          const float w = ww[u];
          a0 += w * bflo(q[u].x); a1 += w * bfhi(q[u].x);
          a2 += w * bflo(q[u].y); a3 += w * bfhi(q[u].y);
          a4 += w * bflo(q[u].z); a5 += w * bfhi(q[u].z);
          a6 += w * bflo(q[u].w); a7 += w * bfhi(q[u].w);
        }
      }
      if (f32m) {
        float4* o4 = (float4*)out + (size_t)n * 96 + c * 2;
        o4[0] = (float4){a0, a1, a2, a3};
        o4[1] = (float4){a4, a5, a6, a7};
      } else {
        uint4 o;
        o.x = (u32)f2bf(a0) | ((u32)f2bf(a1) << 16);
        o.y = (u32)f2bf(a2) | ((u32)f2bf(a3) << 16);
        o.z = (u32)f2bf(a4) | ((u32)f2bf(a5) << 16);
        o.w = (u32)f2bf(a6) | ((u32)f2bf(a7) << 16);
        ((uint4*)out)[(size_t)n * 48 + c] = o;
      }
    }
  }
}

extern "C" void kernel_launch(void* const* d_in, const int* in_sizes, int n_in,
                              void* d_out, int out_size, void* d_ws, size_t ws_size,
                              hipStream_t stream) {
  const void* h  = d_in[0];
  const int*  ci = (const int*)d_in[1];
  const void* Wi = d_in[2];
  const void* Wj = d_in[3];
  const void* ai = d_in[4];
  const void* aj = d_in[5];
  const void* ab = d_in[6];

  char* ws = (char*)d_ws;
  u16*   Wh  = (u16*)(ws + WH_OFF);
  u16*   Bt  = (u16*)(ws + BT_OFF);
  float* v   = (float*)(ws + V_OFF);
  float* si  = (float*)(ws + SI_OFF);
  float* sj  = (float*)(ws + SJ_OFF);
  float* ajf = (float*)(ws + AJF_OFF);
  float* abf = (float*)(ws + ABF_OFF);

  prep_kernel<<<99, 256, 0, stream>>>(h, Wi, Wj, ai, aj, ab, Bt, v, sj, ajf, abf);
  gemm_fused<<<512, 256, 0, stream>>>(h, Bt, v, Wh, si, ajf, sj);
  attn_kernel<<<3277, 256, 0, stream>>>(h, ci, si, sj, abf, Wh, d_out);
}